// Round 6
// baseline (57.669 us; speedup 1.0000x reference)
//
#include <hip/hip_runtime.h>
#include <cstdint>

// DeepSeek-V3 MoE routing, MI355X. T=131072, E=256, G=8x32, topk_group=4, top_k=8.
// One wave per token; lane i owns experts 4i..4i+3.
// R6: direct-exp2 sigmoid (no range reduction — sigmoid derivative damps the
//     input-quantization error: abs err <= rel(e)*sig*(1-sig) ~ 6e-8) and
//     packed VOP3P f32 math (v_pk_mul/add/fma) for the elementwise pipeline.

constexpr int NUM_EXPERTS = 256;
constexpr int TOPK_GROUP  = 4;
constexpr int TOP_K       = 8;
constexpr float ROUTED_SCALING = 2.5f;

typedef float v2f __attribute__((ext_vector_type(2)));

static __device__ __forceinline__ v2f pk_mul(v2f a, v2f b) {
  v2f d; asm("v_pk_mul_f32 %0, %1, %2" : "=v"(d) : "v"(a), "v"(b)); return d;
}
static __device__ __forceinline__ v2f pk_add(v2f a, v2f b) {
  v2f d; asm("v_pk_add_f32 %0, %1, %2" : "=v"(d) : "v"(a), "v"(b)); return d;
}
static __device__ __forceinline__ v2f pk_fma(v2f a, v2f b, v2f c) {
  v2f d; asm("v_pk_fma_f32 %0, %1, %2, %3" : "=v"(d) : "v"(a), "v"(b), "v"(c)); return d;
}

// DPP controls: quad_perm xor1/xor2, row_half_mirror (pairs within 8), row_mirror.
#define DPP_XOR1 0xB1
#define DPP_XOR2 0x4E
#define DPP_HM   0x141
#define DPP_M    0x140

template <int CTRL>
static __device__ __forceinline__ float dpp_f32(float x) {
  return __int_as_float(__builtin_amdgcn_mov_dpp(__float_as_int(x), CTRL, 0xF, 0xF, true));
}
template <int CTRL>
static __device__ __forceinline__ unsigned dpp_u32(unsigned x) {
  return (unsigned)__builtin_amdgcn_mov_dpp((int)x, CTRL, 0xF, 0xF, true);
}

static __device__ __forceinline__ unsigned sortable_f32(float f) {
  const int u = __float_as_int(f);
  const int m = (u >> 31) | 0x80000000;
  return (unsigned)(u ^ m);
}

static __device__ __forceinline__ int mbcnt64(unsigned long long m) {
  return __builtin_amdgcn_mbcnt_hi((unsigned)(m >> 32),
         __builtin_amdgcn_mbcnt_lo((unsigned)m, 0));
}

static __device__ __forceinline__ unsigned umax2(unsigned x, unsigned y) {
  return x > y ? x : y;
}

static __device__ __forceinline__ float nr_recip(float d) {
  const float r0 = __builtin_amdgcn_rcpf(d);
  return __builtin_fmaf(r0, __builtin_fmaf(-d, r0, 1.0f), r0);
}

__global__ __launch_bounds__(256) void moe_route_kernel(
    const float* __restrict__ logits,   // [T, 256]
    const float* __restrict__ bias,     // [256]
    float* __restrict__ out_idx,        // [T, 8] indices as float
    float* __restrict__ out_val,        // [T, 8]
    int n_tokens) {
  const int lane = threadIdx.x & 63;
  const int wid  = threadIdx.x >> 6;
  const int token = blockIdx.x * 4 + wid;   // grid exact: no bounds guard
  __shared__ float2 buf[4][TOP_K];          // per-wave 8 winner (idx_bits, sig)

  // ---- loads (32-bit indexing) ----
  const float4 lv = reinterpret_cast<const float4*>(logits)[token * 64 + lane];
  const float4 bv = reinterpret_cast<const float4*>(bias)[lane];

  // ---- packed direct-exp2 sigmoid: sig = 1/(1 + 2^(-x*log2e)) ----
  const v2f mlog2e = {-1.44269504f, -1.44269504f};
  const v2f one2   = {1.0f, 1.0f};
  const v2f none2  = {-1.0f, -1.0f};
  const v2f xlo = {lv.x, lv.y}, xhi = {lv.z, lv.w};
  const v2f plo = pk_mul(xlo, mlog2e);
  const v2f phi = pk_mul(xhi, mlog2e);
  const v2f elo = {__builtin_amdgcn_exp2f(plo.x), __builtin_amdgcn_exp2f(plo.y)};
  const v2f ehi = {__builtin_amdgcn_exp2f(phi.x), __builtin_amdgcn_exp2f(phi.y)};
  const v2f dlo = pk_add(elo, one2);
  const v2f dhi = pk_add(ehi, one2);
  const v2f rlo = {__builtin_amdgcn_rcpf(dlo.x), __builtin_amdgcn_rcpf(dlo.y)};
  const v2f rhi = {__builtin_amdgcn_rcpf(dhi.x), __builtin_amdgcn_rcpf(dhi.y)};
  const v2f ndlo = pk_mul(dlo, none2);
  const v2f ndhi = pk_mul(dhi, none2);
  const v2f tlo = pk_fma(ndlo, rlo, one2);   // 1 - d*r  (Newton residual)
  const v2f thi = pk_fma(ndhi, rhi, one2);
  const v2f siglo = pk_fma(rlo, tlo, rlo);   // r + r*(1-d*r)
  const v2f sighi = pk_fma(rhi, thi, rhi);
  const v2f blo = {bv.x, bv.y}, bhi = {bv.z, bv.w};
  const v2f swblo = pk_add(siglo, blo);
  const v2f swbhi = pk_add(sighi, bhi);
  const float sig0 = siglo.x, sig1 = siglo.y, sig2 = sighi.x, sig3 = sighi.y;
  const float swb0 = swblo.x, swb1 = swblo.y, swb2 = swbhi.x, swb3 = swbhi.y;

  // ---- group score: top-2 sum within each group (lanes 8g..8g+7), DPP merge ----
  const float h1 = fmaxf(swb0, swb1), l1 = fminf(swb0, swb1);
  const float h2 = fmaxf(swb2, swb3), l2 = fminf(swb2, swb3);
  float m1 = fmaxf(h1, h2);
  float m2 = fmaxf(fminf(h1, h2), fmaxf(l1, l2));
#define MERGE_LEV(CTRL)                                            \
  {                                                                \
    const float o1 = dpp_f32<CTRL>(m1);                            \
    const float o2 = dpp_f32<CTRL>(m2);                            \
    const float nm1 = fmaxf(m1, o1);                               \
    const float nm2 = fmaxf(fminf(m1, o1), fmaxf(m2, o2));         \
    m1 = nm1; m2 = nm2;                                            \
  }
  MERGE_LEV(DPP_XOR1)
  MERGE_LEV(DPP_XOR2)
  MERGE_LEV(DPP_HM)
#undef MERGE_LEV
  const float gscore = m1 + m2;

  // ---- group rank via one pairwise ballot ----
  const int g = lane >> 3;
  const int a = lane & 7;
  const float gs_o = __shfl(gscore, a << 3);
  const unsigned long long gm =
      __ballot((gs_o > gscore) || (gs_o == gscore && a < g));
  const int grank = __popc((unsigned)(gm >> (g << 3)) & 0xFFu);
  const bool gsel = grank < TOPK_GROUP;

  // ---- 32-bit sortable keys; non-selected groups -> 0 ----
  const int ebase = lane << 2;
  const unsigned k0 = gsel ? sortable_f32(swb0) : 0u;
  const unsigned k1 = gsel ? sortable_f32(swb1) : 0u;
  const unsigned k2 = gsel ? sortable_f32(swb2) : 0u;
  const unsigned k3 = gsel ? sortable_f32(swb3) : 0u;

  // ---- radix select on HIGH 16 bits ----
  unsigned t16 = 0u;
#pragma unroll
  for (int bit = 15; bit >= 0; --bit) {
    const unsigned test = (t16 | (1u << bit)) << 16;
    const int c = __popcll(__ballot(k0 >= test)) + __popcll(__ballot(k1 >= test))
                + __popcll(__ballot(k2 >= test)) + __popcll(__ballot(k3 >= test));
    t16 = (c >= TOP_K) ? (t16 | (1u << bit)) : t16;
  }
  const unsigned tf = t16 << 16;

  bool sel0 = k0 >= tf, sel1 = k1 >= tf, sel2 = k2 >= tf, sel3 = k3 >= tf;
  unsigned long long sm0 = __ballot(sel0), sm1 = __ballot(sel1),
                     sm2 = __ballot(sel2), sm3 = __ballot(sel3);
  const int cnt = __popcll(sm0) + __popcll(sm1) + __popcll(sm2) + __popcll(sm3);

  if (cnt > TOP_K) {   // wave-uniform slow path: ties within the high-16 bucket
    const unsigned tg = tf + 0x10000u;
    const bool c0 = sel0 && (k0 < tg);
    const bool c1 = sel1 && (k1 < tg);
    const bool c2 = sel2 && (k2 < tg);
    const bool c3 = sel3 && (k3 < tg);
    const int nc = __popcll(__ballot(c0)) + __popcll(__ballot(c1))
                 + __popcll(__ballot(c2)) + __popcll(__ballot(c3));
    const int need2 = TOP_K - (cnt - nc);   // 1..8 to admit
    sel0 = sel0 && !c0; sel1 = sel1 && !c1;
    sel2 = sel2 && !c2; sel3 = sel3 && !c3;
    unsigned p0 = c0 ? (((k0 & 0xFFFFu) << 16) | (0xFFFFu - (unsigned)(ebase + 0))) : 0u;
    unsigned p1 = c1 ? (((k1 & 0xFFFFu) << 16) | (0xFFFFu - (unsigned)(ebase + 1))) : 0u;
    unsigned p2 = c2 ? (((k2 & 0xFFFFu) << 16) | (0xFFFFu - (unsigned)(ebase + 2))) : 0u;
    unsigned p3 = c3 ? (((k3 & 0xFFFFu) << 16) | (0xFFFFu - (unsigned)(ebase + 3))) : 0u;
    for (int r = 0; r < need2; ++r) {       // wave-uniform trips (exp. 1)
      unsigned mm = umax2(umax2(p0, p1), umax2(p2, p3));
      mm = umax2(mm, dpp_u32<DPP_XOR1>(mm));
      mm = umax2(mm, dpp_u32<DPP_XOR2>(mm));
      mm = umax2(mm, dpp_u32<DPP_HM>(mm));               // uniform within 8
      mm = umax2(mm, dpp_u32<DPP_M>(mm));                // uniform within 16
      mm = umax2(mm, (unsigned)__shfl_xor((int)mm, 16));
      mm = umax2(mm, (unsigned)__shfl_xor((int)mm, 32)); // wave-uniform
      const bool w0 = (p0 == mm), w1 = (p1 == mm), w2 = (p2 == mm), w3 = (p3 == mm);
      sel0 = sel0 || w0; sel1 = sel1 || w1;
      sel2 = sel2 || w2; sel3 = sel3 || w3;
      p0 = w0 ? 0u : p0; p1 = w1 ? 0u : p1;
      p2 = w2 ? 0u : p2; p3 = w3 ? 0u : p3;
    }
    sm0 = __ballot(sel0); sm1 = __ballot(sel1);
    sm2 = __ballot(sel2); sm3 = __ballot(sel3);
  }

  // ---- compact exactly-8 winners into LDS (slot = rank by expert idx) ----
  const int sbelow = mbcnt64(sm0) + mbcnt64(sm1) + mbcnt64(sm2) + mbcnt64(sm3);
  const int slot0 = sbelow;
  const int slot1 = slot0 + (int)sel0;
  const int slot2 = slot1 + (int)sel1;
  const int slot3 = slot2 + (int)sel2;

  float2* tb = buf[wid];
  if (sel0) tb[slot0] = make_float2(__int_as_float(ebase + 0), sig0);
  if (sel1) tb[slot1] = make_float2(__int_as_float(ebase + 1), sig1);
  if (sel2) tb[slot2] = make_float2(__int_as_float(ebase + 2), sig2);
  if (sel3) tb[slot3] = make_float2(__int_as_float(ebase + 3), sig3);
  asm volatile("s_waitcnt lgkmcnt(0)" ::: "memory");  // same-wave LDS RAW

  // ---- readback (lane l mirrors winner l&7), renormalize via DPP sum ----
  const int l8 = lane & 7;
  const float2 w = tb[l8];
  const float widx = (float)__float_as_int(w.x);
  const float wsig = w.y;
  float ssum = wsig;
  ssum += dpp_f32<DPP_XOR1>(ssum);
  ssum += dpp_f32<DPP_XOR2>(ssum);
  ssum += dpp_f32<DPP_HM>(ssum);
  const float val = wsig * nr_recip(ssum + 1e-20f) * ROUTED_SCALING;

  // ---- final order via one pairwise ballot: winner a=(l&7) vs b=(l>>3) ----
  const int b = lane >> 3;
  const float v_o = __shfl(val, b);
  const float i_o = __shfl(widx, b);
  const unsigned long long rm =
      __ballot((val > v_o) || (val == v_o && widx < i_o));
  const int rank = __popc((unsigned)(rm >> (l8 << 3)) & 0xFFu);

  if (lane < TOP_K) {
    const int obase = token * TOP_K + rank;
    out_idx[obase] = widx;
    out_val[obase] = val;
  }
}

extern "C" void kernel_launch(void* const* d_in, const int* in_sizes, int n_in,
                              void* d_out, int out_size, void* d_ws, size_t ws_size,
                              hipStream_t stream) {
  const float* logits = (const float*)d_in[0];
  const float* bias   = (const float*)d_in[1];
  float* out = (float*)d_out;

  const int n_tokens = in_sizes[0] / NUM_EXPERTS;
  float* out_idx = out;
  float* out_val = out + (size_t)n_tokens * TOP_K;

  const int blocks = (n_tokens + 3) / 4;   // 4 waves (tokens) per 256-thread block
  moe_route_kernel<<<blocks, 256, 0, stream>>>(logits, bias, out_idx, out_val, n_tokens);
}